// Round 1
// baseline (188.905 us; speedup 1.0000x reference)
//
#include <hip/hip_runtime.h>
#include <hip/hip_bf16.h>
#include <math.h>

#define INV_T (1.0f / 0.07f)

typedef __bf16 bf16x8 __attribute__((ext_vector_type(8)));
typedef float f32x4 __attribute__((ext_vector_type(4)));

__device__ __forceinline__ void gld16(const void* g, void* l) {
    __builtin_amdgcn_global_load_lds(
        (const __attribute__((address_space(1))) unsigned int*)g,
        (__attribute__((address_space(3))) unsigned int*)l,
        16, 0, 0);
}

// ---------------- normalize + bf16 pack + positive dot + S-zero ------------
__global__ __launch_bounds__(256) void norm_kernel(
    const float4* __restrict__ f1, const float4* __restrict__ f2,
    ushort4* __restrict__ F, float* __restrict__ S, float* __restrict__ P,
    int B) {
    const int i = blockIdx.x;
    const int t = threadIdx.x;

    float4 x = f1[i * 256 + t];
    float4 y = f2[i * 256 + t];

    float s1 = x.x * x.x + x.y * x.y + x.z * x.z + x.w * x.w;
    float s2 = y.x * y.x + y.y * y.y + y.z * y.z + y.w * y.w;
    float dd = x.x * y.x + x.y * y.y + x.z * y.z + x.w * y.w;

    for (int o = 32; o > 0; o >>= 1) {
        s1 += __shfl_down(s1, o);
        s2 += __shfl_down(s2, o);
        dd += __shfl_down(dd, o);
    }
    __shared__ float red[4][3];
    const int wv = t >> 6, ln = t & 63;
    if (ln == 0) { red[wv][0] = s1; red[wv][1] = s2; red[wv][2] = dd; }
    __syncthreads();
    s1 = red[0][0] + red[1][0] + red[2][0] + red[3][0];
    s2 = red[0][1] + red[1][1] + red[2][1] + red[3][1];
    dd = red[0][2] + red[1][2] + red[2][2] + red[3][2];

    const float rn1 = 1.0f / fmaxf(sqrtf(s1), 1e-12f);
    const float rn2 = 1.0f / fmaxf(sqrtf(s2), 1e-12f);

    union { ushort4 u; __hip_bfloat16 h[4]; } p;
    p.h[0] = __float2bfloat16(x.x * rn1);
    p.h[1] = __float2bfloat16(x.y * rn1);
    p.h[2] = __float2bfloat16(x.z * rn1);
    p.h[3] = __float2bfloat16(x.w * rn1);
    F[(size_t)i * 256 + t] = p.u;
    p.h[0] = __float2bfloat16(y.x * rn2);
    p.h[1] = __float2bfloat16(y.y * rn2);
    p.h[2] = __float2bfloat16(y.z * rn2);
    p.h[3] = __float2bfloat16(y.w * rn2);
    F[(size_t)(B + i) * 256 + t] = p.u;

    if (t == 0) {
        P[i] = dd * rn1 * rn2;
        S[i] = 0.0f;
        S[B + i] = 0.0f;
    }
}

// ---------------- fused sim-GEMM, 256x256 tile, 8-phase counted-vmcnt ------
// 8 waves (2Mx4N), per-wave 128x64 output, BK=64, 2 LDS buffers (128 KB).
// Upper-triangle tile set ti<=tj (528 tiles); epilogue masks gRow<gCol and
// credits exp() to both S[gRow] and S[gCol].
// LDS chunk XOR-swizzle: slot j at row r holds global chunk j^(r&7)
// (pre-swizzled global source, linear global_load_lds dest, swizzled reads).

#define BARRIER() asm volatile("s_barrier" ::: "memory")
#define VMCNT6()  asm volatile("s_waitcnt vmcnt(6)" ::: "memory")
#define VMCNT0()  asm volatile("s_waitcnt vmcnt(0)" ::: "memory")

#define QUAD_MFMA(MH, NH)                                                     \
    _Pragma("unroll") for (int mi = 0; mi < 4; ++mi)                          \
    _Pragma("unroll") for (int ni = 0; ni < 2; ++ni)                          \
    _Pragma("unroll") for (int ks = 0; ks < 2; ++ks)                          \
        acc[(MH) * 4 + mi][(NH) * 2 + ni] =                                   \
            __builtin_amdgcn_mfma_f32_16x16x32_bf16(                          \
                af[mi][ks], bf[NH][ni][ks],                                   \
                acc[(MH) * 4 + mi][(NH) * 2 + ni], 0, 0, 0);

#define PH_COMPUTE(MH, NH)                                                    \
    BARRIER();                                                                \
    asm volatile("s_waitcnt lgkmcnt(0)" ::: "memory");                        \
    __builtin_amdgcn_sched_barrier(0);                                        \
    __builtin_amdgcn_s_setprio(1);                                            \
    QUAD_MFMA(MH, NH);                                                        \
    __builtin_amdgcn_s_setprio(0);                                            \
    __builtin_amdgcn_sched_barrier(0);

__global__ __launch_bounds__(512, 2) void sim_kernel(
    const ushort* __restrict__ F, float* __restrict__ S, int N) {
    (void)N;
    // [buf][A=0/B=1][half][128 rows x 64 cols] bf16 = 128 KB
    __shared__ __align__(16) ushort lds[2][2][2][128 * 64];

    // tile decode: k = tj*(tj+1)/2 + ti, ti <= tj
    const int k = blockIdx.x;
    int tj = (int)((sqrtf(8.0f * (float)k + 1.0f) - 1.0f) * 0.5f);
    while ((tj + 1) * (tj + 2) / 2 <= k) ++tj;
    while (tj * (tj + 1) / 2 > k) --tj;
    const int ti = k - tj * (tj + 1) / 2;
    const int bRow = ti * 256, bCol = tj * 256;

    const int tid = threadIdx.x;
    const int wave = tid >> 6, lane = tid & 63;
    const int wr = wave >> 2, wc = wave & 3;      // 2 x 4 wave grid
    const int quad = lane >> 4, l16 = lane & 15;
    const int swz = l16 & 7;

    // staging: thread stages chunks tid and tid+512 of a 128x64 half-tile
    const int r0 = tid >> 3;                          // 0..63
    const int scol = ((tid & 7) ^ (r0 & 7)) * 8;      // pre-swizzled src chunk
    const size_t gA = (size_t)(bRow + r0) * 1024 + scol;
    const size_t gB = (size_t)(bCol + r0) * 1024 + scol;

    auto stage = [&](int bsel, int ab, int h, int kb) {
        const ushort* g = F + (ab ? gB : gA) + (size_t)h * (128 * 1024) + kb;
        ushort* l = &lds[bsel][ab][h][tid * 8];
        gld16(g, l);                       // rows r0
        gld16(g + 64 * 1024, l + 512 * 8); // rows r0+64
    };

    bf16x8 af[4][2];      // A frags of current m-half
    bf16x8 bf[2][2][2];   // all B frags of current K-tile [nh][ni][ks]
    f32x4 acc[8][4];
#pragma unroll
    for (int a = 0; a < 8; ++a)
#pragma unroll
        for (int b = 0; b < 4; ++b) acc[a][b] = (f32x4){0.0f, 0.0f, 0.0f, 0.0f};

    auto loadA = [&](int bsel, int mh) {
#pragma unroll
        for (int mi = 0; mi < 4; ++mi)
#pragma unroll
            for (int ks = 0; ks < 2; ++ks)
                af[mi][ks] = *(const bf16x8*)&lds[bsel][0][wr]
                    [(mh * 64 + mi * 16 + l16) * 64 + ((ks * 4 + quad) ^ swz) * 8];
    };
    auto loadB = [&](int bsel) {
#pragma unroll
        for (int nh = 0; nh < 2; ++nh)
#pragma unroll
            for (int ni = 0; ni < 2; ++ni)
#pragma unroll
                for (int ks = 0; ks < 2; ++ks)
                    bf[nh][ni][ks] = *(const bf16x8*)&lds[bsel][1][wc >> 1]
                        [((wc & 1) * 64 + nh * 32 + ni * 16 + l16) * 64 +
                         ((ks * 4 + quad) ^ swz) * 8];
    };

    // ---- prologue: tile0 full into buf0; tile1 {B0,B1,A0} into buf1 ----
    stage(0, 0, 0, 0); stage(0, 0, 1, 0); stage(0, 1, 0, 0); stage(0, 1, 1, 0);
    stage(1, 1, 0, 64); stage(1, 1, 1, 64); stage(1, 0, 0, 64);
    VMCNT6();   // tile0 landed; tile1's 3 stages may stay in flight
    BARRIER();

#pragma unroll 1
    for (int it = 0; it < 7; ++it) {
        const int kb0 = it * 128;  // K offset of tile t0 = 2*it
        // ---------- K-tile t0 (buf0) ----------
        // ph1 (0,0): read A-mh0 + all B; stage buf1.A1 <- t1
        loadA(0, 0); loadB(0);
        stage(1, 0, 1, kb0 + 64);
        PH_COMPUTE(0, 0);
        BARRIER();
        // ph2 (0,1): stage buf0.B0 <- t0+2 (B slots free after ph1)
        stage(0, 1, 0, kb0 + 128);
        PH_COMPUTE(0, 1);
        BARRIER();
        // ph3 (1,0): read A-mh1; stage buf0.B1 <- t0+2
        loadA(0, 1);
        stage(0, 1, 1, kb0 + 128);
        PH_COMPUTE(1, 0);
        BARRIER();
        // ph4 (1,1): stage buf0.A0 <- t0+2 (A slots free after ph3); vmcnt(6)
        stage(0, 0, 0, kb0 + 128);
        PH_COMPUTE(1, 1);
        VMCNT6();   // covers buf1 stages {prev ph6,7,8, ph1} for ph5 reads
        BARRIER();
        // ---------- K-tile t1 (buf1) ----------
        // ph5 (0,0): read A-mh0 + all B; stage buf0.A1 <- t0+2
        loadA(1, 0); loadB(1);
        stage(0, 0, 1, kb0 + 128);
        PH_COMPUTE(0, 0);
        BARRIER();
        // ph6 (0,1): stage buf1.B0 <- t1+2
        stage(1, 1, 0, kb0 + 192);
        PH_COMPUTE(0, 1);
        BARRIER();
        // ph7 (1,0): read A-mh1; stage buf1.B1 <- t1+2
        loadA(1, 1);
        stage(1, 1, 1, kb0 + 192);
        PH_COMPUTE(1, 0);
        BARRIER();
        // ph8 (1,1): stage buf1.A0 <- t1+2; vmcnt(6)
        stage(1, 0, 0, kb0 + 192);
        PH_COMPUTE(1, 1);
        VMCNT6();   // covers buf0 stages {ph2..ph5} for next-iter ph1 reads
        BARRIER();
    }

    // ---- K-tile 14 (buf0); only remaining stage = buf1.A1 <- tile15 ----
    loadA(0, 0); loadB(0);
    stage(1, 0, 1, 960);
    QUAD_MFMA(0, 0);
    QUAD_MFMA(0, 1);
    loadA(0, 1);
    QUAD_MFMA(1, 0);
    QUAD_MFMA(1, 1);
    VMCNT0();
    BARRIER();
    // ---- K-tile 15 (buf1); no stages, compiler-managed waits suffice ----
    loadA(1, 0); loadB(1);
    QUAD_MFMA(0, 0);
    QUAD_MFMA(0, 1);
    loadA(1, 1);
    QUAD_MFMA(1, 0);
    QUAD_MFMA(1, 1);

    // ---- epilogue: e = (gRow<gCol) ? exp((c-1)/T) : 0; row+col sums ----
#pragma unroll
    for (int a = 0; a < 8; ++a)
#pragma unroll
        for (int b = 0; b < 4; ++b)
#pragma unroll
            for (int r = 0; r < 4; ++r) {
                const int gRow = bRow + wr * 128 + (a >> 2) * 64 + (a & 3) * 16 + quad * 4 + r;
                const int gCol = bCol + wc * 64 + (b >> 1) * 32 + (b & 1) * 16 + l16;
                acc[a][b][r] = (gRow < gCol)
                    ? __expf((acc[a][b][r] - 1.0f) * INV_T) : 0.0f;
            }

    // row sums: reduce over l16, atomic per (a, r)
#pragma unroll
    for (int a = 0; a < 8; ++a)
#pragma unroll
        for (int r = 0; r < 4; ++r) {
            const int gRow = bRow + wr * 128 + (a >> 2) * 64 + (a & 3) * 16 + quad * 4 + r;
            float v = acc[a][0][r] + acc[a][1][r] + acc[a][2][r] + acc[a][3][r];
            v += __shfl_xor(v, 1);
            v += __shfl_xor(v, 2);
            v += __shfl_xor(v, 4);
            v += __shfl_xor(v, 8);
            if (l16 == 0) atomicAdd(&S[gRow], v);
        }

    // col sums: reduce over quad, atomic per (b, l16)
#pragma unroll
    for (int b = 0; b < 4; ++b) {
        float cv = 0.0f;
#pragma unroll
        for (int a = 0; a < 8; ++a)
#pragma unroll
            for (int r = 0; r < 4; ++r) cv += acc[a][b][r];
        cv += __shfl_xor(cv, 16);
        cv += __shfl_xor(cv, 32);
        if (quad == 0) {
            const int gCol = bCol + wc * 64 + (b >> 1) * 32 + (b & 1) * 16 + l16;
            atomicAdd(&S[gCol], cv);
        }
    }
}

// ---------------- finalize ----------------
__global__ __launch_bounds__(256) void finalize_kernel(
    const float* __restrict__ S, const float* __restrict__ P,
    float* __restrict__ out, int N, int B) {
    float s = 0.0f;
    for (int i = threadIdx.x; i < N; i += 256) s += __logf(S[i]);
    float pp = 0.0f;
    for (int i = threadIdx.x; i < B; i += 256) pp += P[i];
    for (int o = 32; o > 0; o >>= 1) {
        s += __shfl_down(s, o);
        pp += __shfl_down(pp, o);
    }
    __shared__ float red[4][2];
    if ((threadIdx.x & 63) == 0) {
        red[threadIdx.x >> 6][0] = s;
        red[threadIdx.x >> 6][1] = pp;
    }
    __syncthreads();
    if (threadIdx.x == 0) {
        const float sl = red[0][0] + red[1][0] + red[2][0] + red[3][0];
        const float ps = red[0][1] + red[1][1] + red[2][1] + red[3][1];
        out[0] = INV_T + sl / (float)N - ps * (2.0f * INV_T / (float)N);
    }
}

extern "C" void kernel_launch(void* const* d_in, const int* in_sizes, int n_in,
                              void* d_out, int out_size, void* d_ws, size_t ws_size,
                              hipStream_t stream) {
    const int D = 1024;
    const int B = in_sizes[0] / D;       // 4096
    const int N = 2 * B;                 // 8192
    const int M = N / 256;               // 32 tile rows/cols
    const int ntiles = M * (M + 1) / 2;  // 528

    const float* f1 = (const float*)d_in[0];
    const float* f2 = (const float*)d_in[1];

    __hip_bfloat16* F = (__hip_bfloat16*)d_ws;  // N*D bf16 = 16 MB
    float* S = (float*)((char*)d_ws + (size_t)N * D * sizeof(__hip_bfloat16));
    float* P = S + N;  // B floats

    norm_kernel<<<dim3(B), dim3(256), 0, stream>>>(
        (const float4*)f1, (const float4*)f2, (ushort4*)F, S, P, B);
    sim_kernel<<<dim3(ntiles), dim3(512), 0, stream>>>((const ushort*)F, S, N);
    finalize_kernel<<<dim3(1), dim3(256), 0, stream>>>(S, P, (float*)d_out, N, B);
}